// Round 6
// baseline (279.686 us; speedup 1.0000x reference)
//
#include <hip/hip_runtime.h>
#include <hip/hip_bf16.h>

#define BB 8192
#define DD 256
// zeroed region: S_all (BB) + S_1 (BB) + ticket (64 ints)
#define ZN (2 * BB + 64)

typedef float f32x4 __attribute__((ext_vector_type(4)));
typedef __bf16 bf16x8 __attribute__((ext_vector_type(8)));

// sqrt(log2(e)/0.07): fn rows pre-scaled so MFMA acc = sim * log2(e)/T directly
#define FSCALE 4.53981600f

__device__ __forceinline__ void load16_to_lds(const void* g, void* l) {
    __builtin_amdgcn_global_load_lds(
        (const __attribute__((address_space(1))) unsigned int*)g,
        (__attribute__((address_space(3))) unsigned int*)l,
        16, 0, 0);
}

// ---------------------------------------------------------------------------
// prep: one wave per row. dist_sq vs center, per-row sigma partials, writes
// normalized+scaled row in MFMA FRAGMENT ORDER:
//   flat 16B-cell index = (g*8+kc)*64 + quad*16 + l15, row = g*16+l15,
//   elems [kc*32+quad*8, +8). Also zeroes S_all/S_1/ticket/out.
// ---------------------------------------------------------------------------
__global__ __launch_bounds__(256) void prep_kernel(
    const float* __restrict__ feat, const int* __restrict__ labels,
    const float* __restrict__ center, __hip_bfloat16* __restrict__ fnf,
    float* __restrict__ dist_sq, float* __restrict__ rowsum,
    float* __restrict__ rownsq, float* __restrict__ zacc,
    float* __restrict__ out)
{
    const int gid = blockIdx.x * 256 + threadIdx.x;
    if (gid < ZN) zacc[gid] = 0.0f;
    if (gid == 0) out[0] = 0.0f;

    const int wave = threadIdx.x >> 6;
    const int lane = threadIdx.x & 63;
    const int row  = blockIdx.x * 4 + wave;

    const float4* frow = reinterpret_cast<const float4*>(feat + (size_t)row * DD);
    const float4* crow = reinterpret_cast<const float4*>(center);
    float4 x = frow[lane];
    float4 c = crow[lane];

    float d0 = x.x - c.x, d1 = x.y - c.y, d2 = x.z - c.z, d3 = x.w - c.w;
    float dsq = d0*d0 + d1*d1 + d2*d2 + d3*d3;
    float nsq = x.x*x.x + x.y*x.y + x.z*x.z + x.w*x.w;
    float sx  = x.x + x.y + x.z + x.w;

    #pragma unroll
    for (int m = 1; m < 64; m <<= 1) {
        dsq += __shfl_xor(dsq, m);
        nsq += __shfl_xor(nsq, m);
        sx  += __shfl_xor(sx,  m);
    }

    float rn = FSCALE / fmaxf(sqrtf(nsq), 1e-12f);

    ushort4 u;
    u.x = __builtin_bit_cast(unsigned short, __float2bfloat16(x.x * rn));
    u.y = __builtin_bit_cast(unsigned short, __float2bfloat16(x.y * rn));
    u.z = __builtin_bit_cast(unsigned short, __float2bfloat16(x.z * rn));
    u.w = __builtin_bit_cast(unsigned short, __float2bfloat16(x.w * rn));

    // lane holds elems e=4*lane..+3: kc=lane/8, quad=(lane%8)/2, half=lane&1
    const int g    = row >> 4;
    const int l15r = row & 15;
    const int kc   = lane >> 3;
    const int qd   = (lane & 7) >> 1;
    const int half = lane & 1;
    const size_t cell = (size_t)((g * 8 + kc) * 64 + qd * 16 + l15r);
    reinterpret_cast<ushort4*>(fnf)[cell * 2 + half] = u;

    if (lane == 0) {
        const float m0 = (labels[row] == 0) ? 1.0f : 0.0f;
        dist_sq[row] = dsq;
        rowsum[row]  = sx  * m0;
        rownsq[row]  = nsq * m0;
    }
}

// ---------------------------------------------------------------------------
// gram: fused Gram + masked exp row-sums + last-arrival finalize.
// R4-proven shape: 32 rows/wave (a[2][8] = 64 VGPRs, ~60 total, no spill),
// B tiles (16 cols = 8 KB) async-staged to LDS, double-buffered, shared by
// 4 waves. Grid: 2048 blocks = 64 row-blocks (128 rows) x 32 col-splits
// (256 cols, 16 tiles) -> up to 8 blocks/CU co-resident for latency hiding.
// 32nd arriver per row-block computes the per-row losses into out.
// ---------------------------------------------------------------------------
__global__ __launch_bounds__(256, 4) void gram_kernel(
    const __hip_bfloat16* __restrict__ fnf, const int* __restrict__ labels,
    float* __restrict__ S_all, float* __restrict__ S_1,
    int* __restrict__ ticket, const float* __restrict__ dist_sq,
    const float* __restrict__ rowsum, const float* __restrict__ rownsq,
    const float* __restrict__ rsigma, float* __restrict__ out)
{
    __shared__ __align__(16) char lds[2][8192];
    __shared__ int is_last;
    __shared__ float shred[3][4];

    const int tid  = threadIdx.x;
    const int lane = tid & 63;
    const int wave = tid >> 6;
    const int l15  = lane & 15;
    const int quad = lane >> 4;

    const int cs = blockIdx.x & 31;       // col split (32)
    const int rb = blockIdx.x >> 5;       // row block (64)
    const int rowbase  = rb * 128 + wave * 32;
    const int colstart = cs * 256;

    const bf16x8* __restrict__ F = reinterpret_cast<const bf16x8*>(fnf);

    // A fragments: 2 sub-tiles x 8 k-chunks, coalesced loads
    bf16x8 a[2][8];
    #pragma unroll
    for (int s = 0; s < 2; ++s)
        #pragma unroll
        for (int kc = 0; kc < 8; ++kc)
            a[s][kc] = F[(size_t)(((rowbase >> 4) + s) * 8 + kc) * 64 + lane];

    float sall[2][4], sp1[2][4];
    #pragma unroll
    for (int s = 0; s < 2; ++s)
        #pragma unroll
        for (int r = 0; r < 4; ++r) { sall[s][r] = 0.0f; sp1[s][r] = 0.0f; }

    // stage tile t (8 KB) into buffer b: 256 threads x 2 x 16 B
    auto stage = [&](int t, int b) {
        const char* gsrc = (const char*)fnf +
            (size_t)((colstart + t * 16) >> 4) * 8192 + (size_t)tid * 16;
        load16_to_lds(gsrc,        &lds[b][wave * 1024]);
        load16_to_lds(gsrc + 4096, &lds[b][4096 + wave * 1024]);
    };

    stage(0, 0);

    for (int t = 0; t < 16; ++t) {
        __syncthreads();                 // drains vmcnt: stage(t) landed
        if (t + 1 < 16) stage(t + 1, (t + 1) & 1);

        const bf16x8* Bt = reinterpret_cast<const bf16x8*>(lds[t & 1]);
        f32x4 acc0 = {0,0,0,0}, acc1 = {0,0,0,0};
        #pragma unroll
        for (int kc = 0; kc < 8; ++kc) {
            bf16x8 b = Bt[kc * 64 + lane];
            acc0 = __builtin_amdgcn_mfma_f32_16x16x32_bf16(a[0][kc], b, acc0, 0, 0, 0);
            acc1 = __builtin_amdgcn_mfma_f32_16x16x32_bf16(a[1][kc], b, acc1, 0, 0, 0);
        }

        const int colbase = colstart + t * 16;
        const int bcol = colbase + l15;
        const float w1 = (float)labels[bcol];

        if (colbase + 16 > rowbase && colbase < rowbase + 32) {
            #pragma unroll
            for (int r = 0; r < 4; ++r) {
                const int row0 = rowbase + quad * 4 + r;
                float e0 = (row0 == bcol) ? 0.0f : exp2f(acc0[r]);
                float e1 = (row0 + 16 == bcol) ? 0.0f : exp2f(acc1[r]);
                sall[0][r] += e0; sp1[0][r] = fmaf(e0, w1, sp1[0][r]);
                sall[1][r] += e1; sp1[1][r] = fmaf(e1, w1, sp1[1][r]);
            }
        } else {
            #pragma unroll
            for (int r = 0; r < 4; ++r) {
                float e0 = exp2f(acc0[r]);
                float e1 = exp2f(acc1[r]);
                sall[0][r] += e0; sp1[0][r] = fmaf(e0, w1, sp1[0][r]);
                sall[1][r] += e1; sp1[1][r] = fmaf(e1, w1, sp1[1][r]);
            }
        }
    }

    // reduce over 16 cols held across low lane bits, one atomic/row/block
    #pragma unroll
    for (int s = 0; s < 2; ++s)
        #pragma unroll
        for (int r = 0; r < 4; ++r) {
            float va = sall[s][r];
            float v1 = sp1[s][r];
            #pragma unroll
            for (int m = 1; m < 16; m <<= 1) {
                va += __shfl_xor(va, m);
                v1 += __shfl_xor(v1, m);
            }
            if (l15 == 0) {
                const int grow = rowbase + s * 16 + quad * 4 + r;
                atomicAdd(&S_all[grow], va);
                atomicAdd(&S_1[grow],  v1);
            }
        }

    // ---- last-arrival finalize for this row-block (128 rows) ----
    __threadfence();
    __syncthreads();
    if (tid == 0) {
        int old = __hip_atomic_fetch_add(&ticket[rb], 1, __ATOMIC_ACQ_REL,
                                         __HIP_MEMORY_SCOPE_AGENT);
        is_last = (old == 31) ? 1 : 0;
    }
    __syncthreads();
    if (!is_last) return;

    // sigma stats (once per row-block; reads are L2-hot)
    float cnt = 0.0f, sx = 0.0f, snsq = 0.0f;
    for (int k = tid; k < BB; k += 256) {
        cnt  += (labels[k] == 0) ? 1.0f : 0.0f;
        sx   += rowsum[k];
        snsq += rownsq[k];
    }
    #pragma unroll
    for (int m = 1; m < 64; m <<= 1) {
        cnt  += __shfl_xor(cnt,  m);
        sx   += __shfl_xor(sx,   m);
        snsq += __shfl_xor(snsq, m);
    }
    if (lane == 0) { shred[0][wave] = cnt; shred[1][wave] = sx; shred[2][wave] = snsq; }
    __syncthreads();
    const float n0   = shred[0][0] + shred[0][1] + shred[0][2] + shred[0][3];
    const float tsx  = shred[1][0] + shred[1][1] + shred[1][2] + shred[1][3];
    const float tnsq = shred[2][0] + shred[2][1] + shred[2][2] + shred[2][3];

    const float n_el = n0 * (float)DD;
    const float mean = tsx / n_el;
    const float var  = (tnsq - n_el * mean * mean) / (n_el - 1.0f);
    const float sigma_new  = 0.9f * rsigma[0] + 0.1f * sqrtf(var);
    const float m_adaptive = 0.5f + 0.3f * sigma_new + 0.3f * (1.0f - 224.0f / 900.0f);

    float tot = 0.0f;
    if (tid < 128) {
        const int row = rb * 128 + tid;
        const int l = labels[row];
        const float dsq = dist_sq[row];

        const float r_center = (l == 0) ? dsq : 0.0f;
        const float r_margin = (l == 1) ? fmaxf(m_adaptive - sqrtf(dsq), 0.0f) : 0.0f;

        const float sallv = __hip_atomic_load(&S_all[row], __ATOMIC_RELAXED,
                                              __HIP_MEMORY_SCOPE_AGENT);
        const float s1v   = __hip_atomic_load(&S_1[row],  __ATOMIC_RELAXED,
                                              __HIP_MEMORY_SCOPE_AGENT);
        const float s0v   = sallv - s1v;
        const float pos = (l == 0) ? s0v : s1v;
        const float neg = (l == 0) ? s1v : s0v;

        const float n1 = (float)BB - n0;
        const float cnt_same = ((l == 0) ? n0 : n1) - 1.0f;
        const float cnt_diff = (l == 0) ? n1 : n0;

        float r_con = 0.0f;
        if (cnt_same > 0.0f && cnt_diff > 0.0f)
            r_con = logf(pos + neg + 1e-8f) - logf(pos);

        tot = (r_center + r_margin + 0.5f * r_con) * (1.0f / (float)BB);
    }

    #pragma unroll
    for (int m = 1; m < 64; m <<= 1) tot += __shfl_xor(tot, m);
    if (lane == 0 && wave < 2) atomicAdd(out, tot);
}

// ---------------------------------------------------------------------------
// launch: 2 kernel nodes total.
// ---------------------------------------------------------------------------
extern "C" void kernel_launch(void* const* d_in, const int* in_sizes, int n_in,
                              void* d_out, int out_size, void* d_ws, size_t ws_size,
                              hipStream_t stream) {
    const float* feat   = (const float*)d_in[0];
    const int*   labels = (const int*)d_in[1];
    const float* center = (const float*)d_in[2];
    const float* rsigma = (const float*)d_in[3];
    float* out = (float*)d_out;

    char* ws = (char*)d_ws;
    __hip_bfloat16* fnf = (__hip_bfloat16*)ws;                    // B*D bf16 = 4 MB, fragment order
    float* dist_sq = (float*)(ws + (size_t)BB * DD * 2);          // B floats
    float* S_all   = dist_sq + BB;                                // B floats   (zeroed)
    float* S_1     = S_all + BB;                                  // B floats   (zeroed)
    int*   ticket  = (int*)(S_1 + BB);                            // 64 ints    (zeroed)
    float* rowsum  = (float*)(ticket + 64);                       // B floats
    float* rownsq  = rowsum + BB;                                 // B floats

    prep_kernel<<<dim3(BB / 4), dim3(256), 0, stream>>>(feat, labels, center, fnf,
                                                        dist_sq, rowsum, rownsq, S_all, out);
    gram_kernel<<<dim3(64 * 32), dim3(256), 0, stream>>>(fnf, labels, S_all, S_1,
                                                         ticket, dist_sq, rowsum, rownsq,
                                                         rsigma, out);
}

// Round 7
// 131.883 us; speedup vs baseline: 2.1207x; 2.1207x over previous
//
#include <hip/hip_runtime.h>
#include <hip/hip_bf16.h>

#define BB 8192
#define DD 256
// zeroed region: S_all (BB) + S_1 (BB)
#define ZN (2 * BB)

typedef float f32x4 __attribute__((ext_vector_type(4)));
typedef __bf16 bf16x8 __attribute__((ext_vector_type(8)));

// sqrt(log2(e)/0.07): fn rows pre-scaled so MFMA acc = sim * log2(e)/T directly
#define FSCALE 4.53981600f

__device__ __forceinline__ void load16_to_lds(const void* g, void* l) {
    __builtin_amdgcn_global_load_lds(
        (const __attribute__((address_space(1))) unsigned int*)g,
        (__attribute__((address_space(3))) unsigned int*)l,
        16, 0, 0);
}

// ---------------------------------------------------------------------------
// prep: one wave per row. dist_sq vs center, per-row sigma partials, writes
// normalized+scaled row in MFMA FRAGMENT ORDER:
//   flat 16B-cell index = (g*8+kc)*64 + quad*16 + l15, row = g*16+l15,
//   elems [kc*32+quad*8, +8). Also zeroes S_all/S_1/out.
// ---------------------------------------------------------------------------
__global__ __launch_bounds__(256) void prep_kernel(
    const float* __restrict__ feat, const int* __restrict__ labels,
    const float* __restrict__ center, __hip_bfloat16* __restrict__ fnf,
    float* __restrict__ dist_sq, float* __restrict__ rowsum,
    float* __restrict__ rownsq, float* __restrict__ zacc,
    float* __restrict__ out)
{
    const int gid = blockIdx.x * 256 + threadIdx.x;
    if (gid < ZN) zacc[gid] = 0.0f;
    if (gid == 0) out[0] = 0.0f;

    const int wave = threadIdx.x >> 6;
    const int lane = threadIdx.x & 63;
    const int row  = blockIdx.x * 4 + wave;

    const float4* frow = reinterpret_cast<const float4*>(feat + (size_t)row * DD);
    const float4* crow = reinterpret_cast<const float4*>(center);
    float4 x = frow[lane];
    float4 c = crow[lane];

    float d0 = x.x - c.x, d1 = x.y - c.y, d2 = x.z - c.z, d3 = x.w - c.w;
    float dsq = d0*d0 + d1*d1 + d2*d2 + d3*d3;
    float nsq = x.x*x.x + x.y*x.y + x.z*x.z + x.w*x.w;
    float sx  = x.x + x.y + x.z + x.w;

    #pragma unroll
    for (int m = 1; m < 64; m <<= 1) {
        dsq += __shfl_xor(dsq, m);
        nsq += __shfl_xor(nsq, m);
        sx  += __shfl_xor(sx,  m);
    }

    float rn = FSCALE / fmaxf(sqrtf(nsq), 1e-12f);

    ushort4 u;
    u.x = __builtin_bit_cast(unsigned short, __float2bfloat16(x.x * rn));
    u.y = __builtin_bit_cast(unsigned short, __float2bfloat16(x.y * rn));
    u.z = __builtin_bit_cast(unsigned short, __float2bfloat16(x.z * rn));
    u.w = __builtin_bit_cast(unsigned short, __float2bfloat16(x.w * rn));

    // lane holds elems e=4*lane..+3: kc=lane/8, quad=(lane%8)/2, half=lane&1
    const int g    = row >> 4;
    const int l15r = row & 15;
    const int kc   = lane >> 3;
    const int qd   = (lane & 7) >> 1;
    const int half = lane & 1;
    const size_t cell = (size_t)((g * 8 + kc) * 64 + qd * 16 + l15r);
    reinterpret_cast<ushort4*>(fnf)[cell * 2 + half] = u;

    if (lane == 0) {
        const float m0 = (labels[row] == 0) ? 1.0f : 0.0f;
        dist_sq[row] = dsq;
        rowsum[row]  = sx  * m0;
        rownsq[row]  = nsq * m0;
    }
}

// ---------------------------------------------------------------------------
// gram: SYMMETRIC fused Gram + masked exp sums. Only upper-triangular 128x128
// chunk pairs are computed (2080 of 4096): each off-diagonal tile contributes
// row-sums to chunk u's rows AND col-sums to chunk v's rows (e_ij == e_ji).
// Enumeration: bid=(d,u), v=(u+d)&63, d in [0,32], skip (d==32 && u>=32).
// Per wave: 32 rows (a[2][8]); B tiles (16 cols, 8 KB) async-staged to LDS,
// double-buffered. Col-sums combined across waves/tiles in LDS, flushed once.
// NO device-scope fences (R5/R6 lesson: buffer_wbl2 serializes ~86ns/block).
// ---------------------------------------------------------------------------
__global__ __launch_bounds__(256, 2) void gram_kernel(
    const __hip_bfloat16* __restrict__ fnf, const int* __restrict__ labels,
    float* __restrict__ S_all, float* __restrict__ S_1)
{
    __shared__ __align__(16) char lds[2][8192];
    __shared__ float colacc[2][128];

    const int tid  = threadIdx.x;
    const int lane = tid & 63;
    const int wave = tid >> 6;
    const int l15  = lane & 15;
    const int quad = lane >> 4;

    const int dd = blockIdx.x >> 6;       // chunk distance 0..32
    const int u  = blockIdx.x & 63;       // row chunk
    if (dd == 32 && u >= 32) return;      // dedupe antipodal pairs
    const int v  = (u + dd) & 63;         // col chunk
    const bool diag = (dd == 0);

    const int rowbase  = u * 128 + wave * 32;
    const int colstart = v * 128;

    // zero colacc (before first barrier)
    ((float*)colacc)[tid] = 0.0f;

    const bf16x8* __restrict__ F = reinterpret_cast<const bf16x8*>(fnf);

    // A fragments: 2 sub-tiles x 8 k-chunks, coalesced
    bf16x8 a[2][8];
    const int rc = rowbase >> 4;
    #pragma unroll
    for (int s = 0; s < 2; ++s)
        #pragma unroll
        for (int kc = 0; kc < 8; ++kc)
            a[s][kc] = F[(size_t)((rc + s) * 8 + kc) * 64 + lane];

    // this lane's row labels (for col-sum weighting): row = rowbase+s*16+quad*4+r
    float lrow[2][4];
    #pragma unroll
    for (int s = 0; s < 2; ++s)
        #pragma unroll
        for (int r = 0; r < 4; ++r)
            lrow[s][r] = (float)labels[rowbase + s * 16 + quad * 4 + r];

    float sall[2][4], sp1[2][4];
    #pragma unroll
    for (int s = 0; s < 2; ++s)
        #pragma unroll
        for (int r = 0; r < 4; ++r) { sall[s][r] = 0.0f; sp1[s][r] = 0.0f; }

    // stage tile t (8 KB = cell group v*8+t) into buffer b
    auto stage = [&](int t, int b) {
        const char* gsrc = (const char*)fnf + (size_t)(v * 8 + t) * 8192 + (size_t)tid * 16;
        load16_to_lds(gsrc,        &lds[b][wave * 1024]);
        load16_to_lds(gsrc + 4096, &lds[b][4096 + wave * 1024]);
    };

    stage(0, 0);

    for (int t = 0; t < 8; ++t) {
        __syncthreads();                 // drains vmcnt: stage(t) landed
        if (t + 1 < 8) stage(t + 1, (t + 1) & 1);

        const bf16x8* Bt = reinterpret_cast<const bf16x8*>(lds[t & 1]);
        f32x4 acc0 = {0,0,0,0}, acc1 = {0,0,0,0};
        #pragma unroll
        for (int kc = 0; kc < 8; ++kc) {
            bf16x8 b = Bt[kc * 64 + lane];
            acc0 = __builtin_amdgcn_mfma_f32_16x16x32_bf16(a[0][kc], b, acc0, 0, 0, 0);
            acc1 = __builtin_amdgcn_mfma_f32_16x16x32_bf16(a[1][kc], b, acc1, 0, 0, 0);
        }

        const int colbase = colstart + t * 16;
        const int bcol = colbase + l15;
        const float w1 = (float)labels[bcol];

        if (diag && colbase + 16 > rowbase && colbase < rowbase + 32) {
            // diagonal zone: exclude j==i; diag blocks contribute row-sums only
            #pragma unroll
            for (int r = 0; r < 4; ++r) {
                const int row0 = rowbase + quad * 4 + r;
                float e0 = (row0 == bcol) ? 0.0f : exp2f(acc0[r]);
                float e1 = (row0 + 16 == bcol) ? 0.0f : exp2f(acc1[r]);
                sall[0][r] += e0; sp1[0][r] = fmaf(e0, w1, sp1[0][r]);
                sall[1][r] += e1; sp1[1][r] = fmaf(e1, w1, sp1[1][r]);
            }
        } else {
            float call = 0.0f, c1 = 0.0f;
            #pragma unroll
            for (int r = 0; r < 4; ++r) {
                float e0 = exp2f(acc0[r]);
                float e1 = exp2f(acc1[r]);
                sall[0][r] += e0; sp1[0][r] = fmaf(e0, w1, sp1[0][r]);
                sall[1][r] += e1; sp1[1][r] = fmaf(e1, w1, sp1[1][r]);
                call += e0 + e1;
                c1 = fmaf(e0, lrow[0][r], fmaf(e1, lrow[1][r], c1));
            }
            if (!diag) {
                // reduce over the 4 quads (rows) -> per-col totals
                call += __shfl_xor(call, 16); c1 += __shfl_xor(c1, 16);
                call += __shfl_xor(call, 32); c1 += __shfl_xor(c1, 32);
                if (lane < 16) {
                    atomicAdd(&colacc[0][t * 16 + l15], call);
                    atomicAdd(&colacc[1][t * 16 + l15], c1);
                }
            }
        }
    }

    // row flush: reduce over 16 cols held across low lane bits
    #pragma unroll
    for (int s = 0; s < 2; ++s)
        #pragma unroll
        for (int r = 0; r < 4; ++r) {
            float va = sall[s][r];
            float v1 = sp1[s][r];
            #pragma unroll
            for (int m = 1; m < 16; m <<= 1) {
                va += __shfl_xor(va, m);
                v1 += __shfl_xor(v1, m);
            }
            if (l15 == 0) {
                const int grow = rowbase + s * 16 + quad * 4 + r;
                atomicAdd(&S_all[grow], va);
                atomicAdd(&S_1[grow],  v1);
            }
        }

    // col flush: one pass after all waves' LDS adds
    __syncthreads();
    if (!diag && tid < 128) {
        const int j = colstart + tid;
        atomicAdd(&S_all[j], colacc[0][tid]);
        atomicAdd(&S_1[j],  colacc[1][tid]);
    }
}

// ---------------------------------------------------------------------------
// finalize: 32 blocks; each redundantly computes sigma stats (L2-hot), then
// per-row losses for its 256 rows + mean reduction into out[0].
// ---------------------------------------------------------------------------
__global__ __launch_bounds__(256) void finalize_kernel(
    const int* __restrict__ labels, const float* __restrict__ dist_sq,
    const float* __restrict__ S_all, const float* __restrict__ S_1,
    const float* __restrict__ rowsum, const float* __restrict__ rownsq,
    const float* __restrict__ rsigma, float* __restrict__ out)
{
    __shared__ float shred[3][4];
    const int tid  = threadIdx.x;
    const int lane = tid & 63;
    const int wave = tid >> 6;

    float cnt = 0.0f, sx = 0.0f, snsq = 0.0f;
    for (int k = tid; k < BB; k += 256) {
        cnt  += (labels[k] == 0) ? 1.0f : 0.0f;
        sx   += rowsum[k];
        snsq += rownsq[k];
    }
    #pragma unroll
    for (int m = 1; m < 64; m <<= 1) {
        cnt  += __shfl_xor(cnt,  m);
        sx   += __shfl_xor(sx,   m);
        snsq += __shfl_xor(snsq, m);
    }
    if (lane == 0) { shred[0][wave] = cnt; shred[1][wave] = sx; shred[2][wave] = snsq; }
    __syncthreads();
    const float n0   = shred[0][0] + shred[0][1] + shred[0][2] + shred[0][3];
    const float tsx  = shred[1][0] + shred[1][1] + shred[1][2] + shred[1][3];
    const float tnsq = shred[2][0] + shred[2][1] + shred[2][2] + shred[2][3];

    const float n_el = n0 * (float)DD;
    const float mean = tsx / n_el;
    const float var  = (tnsq - n_el * mean * mean) / (n_el - 1.0f);
    const float sigma_new  = 0.9f * rsigma[0] + 0.1f * sqrtf(var);
    const float m_adaptive = 0.5f + 0.3f * sigma_new + 0.3f * (1.0f - 224.0f / 900.0f);

    const int i = blockIdx.x * 256 + tid;
    const int l = labels[i];
    const float dsq = dist_sq[i];

    const float r_center = (l == 0) ? dsq : 0.0f;
    const float r_margin = (l == 1) ? fmaxf(m_adaptive - sqrtf(dsq), 0.0f) : 0.0f;

    const float sallv = S_all[i];
    const float s1v   = S_1[i];
    const float s0v   = sallv - s1v;
    const float pos = (l == 0) ? s0v : s1v;
    const float neg = (l == 0) ? s1v : s0v;

    const float n1 = (float)BB - n0;
    const float cnt_same = ((l == 0) ? n0 : n1) - 1.0f;
    const float cnt_diff = (l == 0) ? n1 : n0;

    float r_con = 0.0f;
    if (cnt_same > 0.0f && cnt_diff > 0.0f)
        r_con = logf(pos + neg + 1e-8f) - logf(pos);

    float tot = (r_center + r_margin + 0.5f * r_con) * (1.0f / (float)BB);

    #pragma unroll
    for (int m = 1; m < 64; m <<= 1) tot += __shfl_xor(tot, m);
    if (lane == 0) atomicAdd(out, tot);
}

// ---------------------------------------------------------------------------
// launch: 3 kernel nodes.
// ---------------------------------------------------------------------------
extern "C" void kernel_launch(void* const* d_in, const int* in_sizes, int n_in,
                              void* d_out, int out_size, void* d_ws, size_t ws_size,
                              hipStream_t stream) {
    const float* feat   = (const float*)d_in[0];
    const int*   labels = (const int*)d_in[1];
    const float* center = (const float*)d_in[2];
    const float* rsigma = (const float*)d_in[3];
    float* out = (float*)d_out;

    char* ws = (char*)d_ws;
    __hip_bfloat16* fnf = (__hip_bfloat16*)ws;                    // B*D bf16 = 4 MB, fragment order
    float* dist_sq = (float*)(ws + (size_t)BB * DD * 2);          // B floats
    float* S_all   = dist_sq + BB;                                // B floats (zeroed)
    float* S_1     = S_all + BB;                                  // B floats (zeroed)
    float* rowsum  = S_1 + BB;                                    // B floats
    float* rownsq  = rowsum + BB;                                 // B floats

    prep_kernel<<<dim3(BB / 4), dim3(256), 0, stream>>>(feat, labels, center, fnf,
                                                        dist_sq, rowsum, rownsq, S_all, out);
    gram_kernel<<<dim3(64 * 33), dim3(256), 0, stream>>>(fnf, labels, S_all, S_1);
    finalize_kernel<<<dim3(BB / 256), dim3(256), 0, stream>>>(labels, dist_sq, S_all, S_1,
                                                              rowsum, rownsq, rsigma, out);
}

// Round 8
// 128.907 us; speedup vs baseline: 2.1697x; 1.0231x over previous
//
#include <hip/hip_runtime.h>
#include <hip/hip_bf16.h>

#define BB 8192
#define DD 256
// zeroed region: S_all (BB) + S_1 (BB)
#define ZN (2 * BB)

typedef float f32x4 __attribute__((ext_vector_type(4)));
typedef __bf16 bf16x8 __attribute__((ext_vector_type(8)));

// sqrt(log2(e)/0.07): fn rows pre-scaled so MFMA acc = sim * log2(e)/T directly
#define FSCALE 4.53981600f

// ---------------------------------------------------------------------------
// prep: 512 blocks x 16 rows. Per row: dist_sq vs center, sigma partials,
// labels->float. Normalized+scaled bf16 row staged through LDS and written to
// fnf in MFMA FRAGMENT ORDER with perfectly coalesced 16B stores:
//   16B cell index = (g*8+kc)*64 + qd*16 + l15, holding elems
//   [kc*32+qd*8, +8) of row g*16+l15. Also zeroes S_all/S_1/out.
// ---------------------------------------------------------------------------
__global__ __launch_bounds__(256) void prep_kernel(
    const float* __restrict__ feat, const int* __restrict__ labels,
    const float* __restrict__ center, __hip_bfloat16* __restrict__ fnf,
    float* __restrict__ dist_sq, float* __restrict__ rowsum,
    float* __restrict__ rownsq, float* __restrict__ labf,
    float* __restrict__ zacc, float* __restrict__ out)
{
    __shared__ uint2 sh[16][65];   // [row-in-group][lane], padded: stride 130 words

    const int tid  = threadIdx.x;
    const int gid  = blockIdx.x * 256 + tid;
    if (gid < ZN) zacc[gid] = 0.0f;
    if (gid == 0) out[0] = 0.0f;

    const int wave = tid >> 6;
    const int lane = tid & 63;
    const int g    = blockIdx.x;            // row group of 16

    const float4* crow = reinterpret_cast<const float4*>(center);
    const float4 c = crow[lane];

    #pragma unroll
    for (int j = 0; j < 4; ++j) {
        const int r16 = wave * 4 + j;
        const int row = g * 16 + r16;
        const float4 x =
            reinterpret_cast<const float4*>(feat + (size_t)row * DD)[lane];

        float d0 = x.x - c.x, d1 = x.y - c.y, d2 = x.z - c.z, d3 = x.w - c.w;
        float dsq = d0*d0 + d1*d1 + d2*d2 + d3*d3;
        float nsq = x.x*x.x + x.y*x.y + x.z*x.z + x.w*x.w;
        float sx  = x.x + x.y + x.z + x.w;

        #pragma unroll
        for (int m = 1; m < 64; m <<= 1) {
            dsq += __shfl_xor(dsq, m);
            nsq += __shfl_xor(nsq, m);
            sx  += __shfl_xor(sx,  m);
        }

        const float rn = FSCALE / fmaxf(sqrtf(nsq), 1e-12f);

        unsigned ax = __builtin_bit_cast(unsigned short, __float2bfloat16(x.x * rn));
        unsigned ay = __builtin_bit_cast(unsigned short, __float2bfloat16(x.y * rn));
        unsigned az = __builtin_bit_cast(unsigned short, __float2bfloat16(x.z * rn));
        unsigned aw = __builtin_bit_cast(unsigned short, __float2bfloat16(x.w * rn));
        sh[r16][lane] = make_uint2(ax | (ay << 16), az | (aw << 16));

        if (lane == 0) {
            const float m0 = (labels[row] == 0) ? 1.0f : 0.0f;
            dist_sq[row] = dsq;
            rowsum[row]  = sx  * m0;
            rownsq[row]  = nsq * m0;
            labf[row]    = (float)labels[row];
        }
    }

    __syncthreads();

    // write 512 cells (16B each) coalesced: cell c = kc*64 + qd*16 + r15
    #pragma unroll
    for (int c = tid; c < 512; c += 256) {
        const int kc  = c >> 6;
        const int qd  = (c & 63) >> 4;
        const int r15 = c & 15;
        const int ls  = kc * 8 + qd * 2;          // source lane (elems 4*ls..)
        const uint2 lo = sh[r15][ls];
        const uint2 hi = sh[r15][ls + 1];
        reinterpret_cast<uint4*>(fnf)[(size_t)g * 512 + c] =
            make_uint4(lo.x, lo.y, hi.x, hi.y);
    }
}

// ---------------------------------------------------------------------------
// gram: BARRIER-FREE fused Gram + masked exp row-sums.
// No LDS, no __syncthreads, no vmcnt(0) drains: each wave independently holds
// 32 rows (a[2][8]) and streams B fragments straight from L2/L1 (fnf is 4 MB,
// L2-resident; 4 waves/block walk the same col-tiles -> L1 reuse).
// Grid: 1024 blocks = 64 row-blocks (128 rows) x 16 col-splits (512 cols).
// __launch_bounds__(256,3): 3 waves/SIMD of TLP to hide b-load latency.
// ---------------------------------------------------------------------------
__global__ __launch_bounds__(256, 3) void gram_kernel(
    const __hip_bfloat16* __restrict__ fnf, const float* __restrict__ labf,
    float* __restrict__ S_all, float* __restrict__ S_1)
{
    const int tid  = threadIdx.x;
    const int lane = tid & 63;
    const int wave = tid >> 6;
    const int l15  = lane & 15;
    const int quad = lane >> 4;

    const int cs = blockIdx.x & 15;       // col split (16)
    const int rb = blockIdx.x >> 4;       // row block (64)
    const int rowbase  = rb * 128 + wave * 32;
    const int colstart = cs * 512;

    const bf16x8* __restrict__ F = reinterpret_cast<const bf16x8*>(fnf);

    // A fragments: 2 sub-tiles x 8 k-chunks, coalesced
    bf16x8 a[2][8];
    const int rc = rowbase >> 4;
    #pragma unroll
    for (int s = 0; s < 2; ++s)
        #pragma unroll
        for (int kc = 0; kc < 8; ++kc)
            a[s][kc] = F[(size_t)((rc + s) * 8 + kc) * 64 + lane];

    float sall[2][4], sp1[2][4];
    #pragma unroll
    for (int s = 0; s < 2; ++s)
        #pragma unroll
        for (int r = 0; r < 4; ++r) { sall[s][r] = 0.0f; sp1[s][r] = 0.0f; }

    // running pointer to tile t's fragment cells (8 KB per 16-col tile)
    const char* bptr = (const char*)fnf + (size_t)(colstart >> 4) * 8192
                     + (size_t)lane * 16;

    for (int t = 0; t < 32; ++t) {
        const int colbase = colstart + t * 16;
        const float w1 = labf[colbase + l15];

        bf16x8 b[8];
        #pragma unroll
        for (int kc = 0; kc < 8; ++kc)
            b[kc] = *reinterpret_cast<const bf16x8*>(bptr + kc * 1024);
        bptr += 8192;

        f32x4 acc0 = {0,0,0,0}, acc1 = {0,0,0,0};
        #pragma unroll
        for (int kc = 0; kc < 8; ++kc) {
            acc0 = __builtin_amdgcn_mfma_f32_16x16x32_bf16(a[0][kc], b[kc], acc0, 0, 0, 0);
            acc1 = __builtin_amdgcn_mfma_f32_16x16x32_bf16(a[1][kc], b[kc], acc1, 0, 0, 0);
        }

        const int bcol = colbase + l15;
        if (colbase + 16 > rowbase && colbase < rowbase + 32) {
            // diagonal zone: exclude j==i cells
            #pragma unroll
            for (int r = 0; r < 4; ++r) {
                const int row0 = rowbase + quad * 4 + r;
                float e0 = (row0 == bcol) ? 0.0f : exp2f(acc0[r]);
                float e1 = (row0 + 16 == bcol) ? 0.0f : exp2f(acc1[r]);
                sall[0][r] += e0; sp1[0][r] = fmaf(e0, w1, sp1[0][r]);
                sall[1][r] += e1; sp1[1][r] = fmaf(e1, w1, sp1[1][r]);
            }
        } else {
            #pragma unroll
            for (int r = 0; r < 4; ++r) {
                float e0 = exp2f(acc0[r]);
                float e1 = exp2f(acc1[r]);
                sall[0][r] += e0; sp1[0][r] = fmaf(e0, w1, sp1[0][r]);
                sall[1][r] += e1; sp1[1][r] = fmaf(e1, w1, sp1[1][r]);
            }
        }
    }

    // reduce over the 16 cols held across low lane bits, one atomic/row
    #pragma unroll
    for (int s = 0; s < 2; ++s)
        #pragma unroll
        for (int r = 0; r < 4; ++r) {
            float va = sall[s][r];
            float v1 = sp1[s][r];
            #pragma unroll
            for (int m = 1; m < 16; m <<= 1) {
                va += __shfl_xor(va, m);
                v1 += __shfl_xor(v1, m);
            }
            if (l15 == 0) {
                const int grow = rowbase + s * 16 + quad * 4 + r;
                atomicAdd(&S_all[grow], va);
                atomicAdd(&S_1[grow],  v1);
            }
        }
}

// ---------------------------------------------------------------------------
// finalize: 32 blocks; each redundantly computes sigma stats (L2-hot), then
// per-row losses for its 256 rows + mean reduction into out[0].
// ---------------------------------------------------------------------------
__global__ __launch_bounds__(256) void finalize_kernel(
    const int* __restrict__ labels, const float* __restrict__ dist_sq,
    const float* __restrict__ S_all, const float* __restrict__ S_1,
    const float* __restrict__ rowsum, const float* __restrict__ rownsq,
    const float* __restrict__ rsigma, float* __restrict__ out)
{
    __shared__ float shred[3][4];
    const int tid  = threadIdx.x;
    const int lane = tid & 63;
    const int wave = tid >> 6;

    float cnt = 0.0f, sx = 0.0f, snsq = 0.0f;
    for (int k = tid; k < BB; k += 256) {
        cnt  += (labels[k] == 0) ? 1.0f : 0.0f;
        sx   += rowsum[k];
        snsq += rownsq[k];
    }
    #pragma unroll
    for (int m = 1; m < 64; m <<= 1) {
        cnt  += __shfl_xor(cnt,  m);
        sx   += __shfl_xor(sx,   m);
        snsq += __shfl_xor(snsq, m);
    }
    if (lane == 0) { shred[0][wave] = cnt; shred[1][wave] = sx; shred[2][wave] = snsq; }
    __syncthreads();
    const float n0   = shred[0][0] + shred[0][1] + shred[0][2] + shred[0][3];
    const float tsx  = shred[1][0] + shred[1][1] + shred[1][2] + shred[1][3];
    const float tnsq = shred[2][0] + shred[2][1] + shred[2][2] + shred[2][3];

    const float n_el = n0 * (float)DD;
    const float mean = tsx / n_el;
    const float var  = (tnsq - n_el * mean * mean) / (n_el - 1.0f);
    const float sigma_new  = 0.9f * rsigma[0] + 0.1f * sqrtf(var);
    const float m_adaptive = 0.5f + 0.3f * sigma_new + 0.3f * (1.0f - 224.0f / 900.0f);

    const int i = blockIdx.x * 256 + tid;
    const int l = labels[i];
    const float dsq = dist_sq[i];

    const float r_center = (l == 0) ? dsq : 0.0f;
    const float r_margin = (l == 1) ? fmaxf(m_adaptive - sqrtf(dsq), 0.0f) : 0.0f;

    const float sallv = S_all[i];
    const float s1v   = S_1[i];
    const float s0v   = sallv - s1v;
    const float pos = (l == 0) ? s0v : s1v;
    const float neg = (l == 0) ? s1v : s0v;

    const float n1 = (float)BB - n0;
    const float cnt_same = ((l == 0) ? n0 : n1) - 1.0f;
    const float cnt_diff = (l == 0) ? n1 : n0;

    float r_con = 0.0f;
    if (cnt_same > 0.0f && cnt_diff > 0.0f)
        r_con = logf(pos + neg + 1e-8f) - logf(pos);

    float tot = (r_center + r_margin + 0.5f * r_con) * (1.0f / (float)BB);

    #pragma unroll
    for (int m = 1; m < 64; m <<= 1) tot += __shfl_xor(tot, m);
    if (lane == 0) atomicAdd(out, tot);
}

// ---------------------------------------------------------------------------
// launch: 3 kernel nodes.
// ---------------------------------------------------------------------------
extern "C" void kernel_launch(void* const* d_in, const int* in_sizes, int n_in,
                              void* d_out, int out_size, void* d_ws, size_t ws_size,
                              hipStream_t stream) {
    const float* feat   = (const float*)d_in[0];
    const int*   labels = (const int*)d_in[1];
    const float* center = (const float*)d_in[2];
    const float* rsigma = (const float*)d_in[3];
    float* out = (float*)d_out;

    char* ws = (char*)d_ws;
    __hip_bfloat16* fnf = (__hip_bfloat16*)ws;                    // B*D bf16 = 4 MB, fragment order
    float* dist_sq = (float*)(ws + (size_t)BB * DD * 2);          // B floats
    float* S_all   = dist_sq + BB;                                // B floats (zeroed)
    float* S_1     = S_all + BB;                                  // B floats (zeroed)
    float* rowsum  = S_1 + BB;                                    // B floats
    float* rownsq  = rowsum + BB;                                 // B floats
    float* labf    = rownsq + BB;                                 // B floats

    prep_kernel<<<dim3(BB / 16), dim3(256), 0, stream>>>(feat, labels, center, fnf,
                                                         dist_sq, rowsum, rownsq, labf,
                                                         S_all, out);
    gram_kernel<<<dim3(64 * 16), dim3(256), 0, stream>>>(fnf, labf, S_all, S_1);
    finalize_kernel<<<dim3(BB / 256), dim3(256), 0, stream>>>(labels, dist_sq, S_all, S_1,
                                                              rowsum, rownsq, rsigma, out);
}

// Round 9
// 124.516 us; speedup vs baseline: 2.2462x; 1.0353x over previous
//
#include <hip/hip_runtime.h>
#include <hip/hip_bf16.h>

#define BB 8192
#define DD 256
// zeroed region: S_all (BB) + S_1 (BB)
#define ZN (2 * BB)

typedef float f32x4 __attribute__((ext_vector_type(4)));
typedef __bf16 bf16x8 __attribute__((ext_vector_type(8)));

// sqrt(log2(e)/0.07): fn rows pre-scaled so MFMA acc = sim * log2(e)/T directly
#define FSCALE 4.53981600f

// ---------------------------------------------------------------------------
// prep (R4-proven shape): one wave per row. dist_sq vs center, sigma partials,
// labels->float, writes normalized+scaled row in MFMA FRAGMENT ORDER:
//   16B cell index = (g*8+kc)*64 + qd*16 + l15, holding elems
//   [kc*32+qd*8, +8) of row g*16+l15. Also zeroes S_all/S_1/out.
// ---------------------------------------------------------------------------
__global__ __launch_bounds__(256) void prep_kernel(
    const float* __restrict__ feat, const int* __restrict__ labels,
    const float* __restrict__ center, __hip_bfloat16* __restrict__ fnf,
    float* __restrict__ dist_sq, float* __restrict__ rowsum,
    float* __restrict__ rownsq, float* __restrict__ labf,
    float* __restrict__ zacc, float* __restrict__ out)
{
    const int gid = blockIdx.x * 256 + threadIdx.x;
    if (gid < ZN) zacc[gid] = 0.0f;
    if (gid == 0) out[0] = 0.0f;

    const int wave = threadIdx.x >> 6;
    const int lane = threadIdx.x & 63;
    const int row  = blockIdx.x * 4 + wave;

    const float4* frow = reinterpret_cast<const float4*>(feat + (size_t)row * DD);
    const float4* crow = reinterpret_cast<const float4*>(center);
    float4 x = frow[lane];
    float4 c = crow[lane];

    float d0 = x.x - c.x, d1 = x.y - c.y, d2 = x.z - c.z, d3 = x.w - c.w;
    float dsq = d0*d0 + d1*d1 + d2*d2 + d3*d3;
    float nsq = x.x*x.x + x.y*x.y + x.z*x.z + x.w*x.w;
    float sx  = x.x + x.y + x.z + x.w;

    #pragma unroll
    for (int m = 1; m < 64; m <<= 1) {
        dsq += __shfl_xor(dsq, m);
        nsq += __shfl_xor(nsq, m);
        sx  += __shfl_xor(sx,  m);
    }

    float rn = FSCALE / fmaxf(sqrtf(nsq), 1e-12f);

    ushort4 u;
    u.x = __builtin_bit_cast(unsigned short, __float2bfloat16(x.x * rn));
    u.y = __builtin_bit_cast(unsigned short, __float2bfloat16(x.y * rn));
    u.z = __builtin_bit_cast(unsigned short, __float2bfloat16(x.z * rn));
    u.w = __builtin_bit_cast(unsigned short, __float2bfloat16(x.w * rn));

    // lane holds elems e=4*lane..+3: kc=lane/8, qd=(lane%8)/2, half=lane&1
    const int g    = row >> 4;
    const int l15r = row & 15;
    const int kc   = lane >> 3;
    const int qd   = (lane & 7) >> 1;
    const int half = lane & 1;
    const size_t cell = (size_t)((g * 8 + kc) * 64 + qd * 16 + l15r);
    reinterpret_cast<ushort4*>(fnf)[cell * 2 + half] = u;

    if (lane == 0) {
        const float m0 = (labels[row] == 0) ? 1.0f : 0.0f;
        dist_sq[row] = dsq;
        rowsum[row]  = sx  * m0;
        rownsq[row]  = nsq * m0;
        labf[row]    = (float)labels[row];
    }
}

// ---------------------------------------------------------------------------
// gram: BARRIER-FREE fused Gram + masked exp row-sums.
// Each wave independently holds 32 rows (a[2][8]); B fragments stream from
// L2/L1 (fnf is 4 MB, L2-resident; 4 waves/block share col-tiles -> L1 reuse).
// exp via raw v_exp_f32 (__builtin_amdgcn_exp2f): 1 inst vs ~15 for libm
// exp2f — the R8 epilogue was ~395 VALU cyc/tile, dominated by exp expansion.
// Grid: 1024 blocks = 64 row-blocks (128 rows) x 16 col-splits (512 cols).
// ---------------------------------------------------------------------------
__global__ __launch_bounds__(256, 4) void gram_kernel(
    const __hip_bfloat16* __restrict__ fnf, const float* __restrict__ labf,
    float* __restrict__ S_all, float* __restrict__ S_1)
{
    const int tid  = threadIdx.x;
    const int lane = tid & 63;
    const int wave = tid >> 6;
    const int l15  = lane & 15;
    const int quad = lane >> 4;

    const int cs = blockIdx.x & 15;       // col split (16)
    const int rb = blockIdx.x >> 4;       // row block (64)
    const int rowbase  = rb * 128 + wave * 32;
    const int colstart = cs * 512;

    const bf16x8* __restrict__ F = reinterpret_cast<const bf16x8*>(fnf);

    // A fragments: 2 sub-tiles x 8 k-chunks, coalesced
    bf16x8 a[2][8];
    const int rc = rowbase >> 4;
    #pragma unroll
    for (int s = 0; s < 2; ++s)
        #pragma unroll
        for (int kc = 0; kc < 8; ++kc)
            a[s][kc] = F[(size_t)((rc + s) * 8 + kc) * 64 + lane];

    float sall[2][4], sp1[2][4];
    #pragma unroll
    for (int s = 0; s < 2; ++s)
        #pragma unroll
        for (int r = 0; r < 4; ++r) { sall[s][r] = 0.0f; sp1[s][r] = 0.0f; }

    // running pointer to tile t's fragment cells (8 KB per 16-col tile)
    const char* bptr = (const char*)fnf + (size_t)(colstart >> 4) * 8192
                     + (size_t)lane * 16;

    for (int t = 0; t < 32; ++t) {
        const int colbase = colstart + t * 16;
        const float w1 = labf[colbase + l15];

        bf16x8 b[8];
        #pragma unroll
        for (int kc = 0; kc < 8; ++kc)
            b[kc] = *reinterpret_cast<const bf16x8*>(bptr + kc * 1024);
        bptr += 8192;

        f32x4 acc0 = {0,0,0,0}, acc1 = {0,0,0,0};
        #pragma unroll
        for (int kc = 0; kc < 8; ++kc) {
            acc0 = __builtin_amdgcn_mfma_f32_16x16x32_bf16(a[0][kc], b[kc], acc0, 0, 0, 0);
            acc1 = __builtin_amdgcn_mfma_f32_16x16x32_bf16(a[1][kc], b[kc], acc1, 0, 0, 0);
        }

        const int bcol = colbase + l15;
        if (colbase + 16 > rowbase && colbase < rowbase + 32) {
            // diagonal zone: exclude j==i cells
            #pragma unroll
            for (int r = 0; r < 4; ++r) {
                const int row0 = rowbase + quad * 4 + r;
                float e0 = (row0 == bcol) ? 0.0f : __builtin_amdgcn_exp2f(acc0[r]);
                float e1 = (row0 + 16 == bcol) ? 0.0f : __builtin_amdgcn_exp2f(acc1[r]);
                sall[0][r] += e0; sp1[0][r] = fmaf(e0, w1, sp1[0][r]);
                sall[1][r] += e1; sp1[1][r] = fmaf(e1, w1, sp1[1][r]);
            }
        } else {
            #pragma unroll
            for (int r = 0; r < 4; ++r) {
                float e0 = __builtin_amdgcn_exp2f(acc0[r]);
                float e1 = __builtin_amdgcn_exp2f(acc1[r]);
                sall[0][r] += e0; sp1[0][r] = fmaf(e0, w1, sp1[0][r]);
                sall[1][r] += e1; sp1[1][r] = fmaf(e1, w1, sp1[1][r]);
            }
        }
    }

    // reduce over the 16 cols held across low lane bits, one atomic/row
    #pragma unroll
    for (int s = 0; s < 2; ++s)
        #pragma unroll
        for (int r = 0; r < 4; ++r) {
            float va = sall[s][r];
            float v1 = sp1[s][r];
            #pragma unroll
            for (int m = 1; m < 16; m <<= 1) {
                va += __shfl_xor(va, m);
                v1 += __shfl_xor(v1, m);
            }
            if (l15 == 0) {
                const int grow = rowbase + s * 16 + quad * 4 + r;
                atomicAdd(&S_all[grow], va);
                atomicAdd(&S_1[grow],  v1);
            }
        }
}

// ---------------------------------------------------------------------------
// finalize: 32 blocks; each redundantly computes sigma stats (L2-hot), then
// per-row losses for its 256 rows + mean reduction into out[0].
// ---------------------------------------------------------------------------
__global__ __launch_bounds__(256) void finalize_kernel(
    const int* __restrict__ labels, const float* __restrict__ dist_sq,
    const float* __restrict__ S_all, const float* __restrict__ S_1,
    const float* __restrict__ rowsum, const float* __restrict__ rownsq,
    const float* __restrict__ rsigma, float* __restrict__ out)
{
    __shared__ float shred[3][4];
    const int tid  = threadIdx.x;
    const int lane = tid & 63;
    const int wave = tid >> 6;

    float cnt = 0.0f, sx = 0.0f, snsq = 0.0f;
    for (int k = tid; k < BB; k += 256) {
        cnt  += (labels[k] == 0) ? 1.0f : 0.0f;
        sx   += rowsum[k];
        snsq += rownsq[k];
    }
    #pragma unroll
    for (int m = 1; m < 64; m <<= 1) {
        cnt  += __shfl_xor(cnt,  m);
        sx   += __shfl_xor(sx,   m);
        snsq += __shfl_xor(snsq, m);
    }
    if (lane == 0) { shred[0][wave] = cnt; shred[1][wave] = sx; shred[2][wave] = snsq; }
    __syncthreads();
    const float n0   = shred[0][0] + shred[0][1] + shred[0][2] + shred[0][3];
    const float tsx  = shred[1][0] + shred[1][1] + shred[1][2] + shred[1][3];
    const float tnsq = shred[2][0] + shred[2][1] + shred[2][2] + shred[2][3];

    const float n_el = n0 * (float)DD;
    const float mean = tsx / n_el;
    const float var  = (tnsq - n_el * mean * mean) / (n_el - 1.0f);
    const float sigma_new  = 0.9f * rsigma[0] + 0.1f * sqrtf(var);
    const float m_adaptive = 0.5f + 0.3f * sigma_new + 0.3f * (1.0f - 224.0f / 900.0f);

    const int i = blockIdx.x * 256 + tid;
    const int l = labels[i];
    const float dsq = dist_sq[i];

    const float r_center = (l == 0) ? dsq : 0.0f;
    const float r_margin = (l == 1) ? fmaxf(m_adaptive - sqrtf(dsq), 0.0f) : 0.0f;

    const float sallv = S_all[i];
    const float s1v   = S_1[i];
    const float s0v   = sallv - s1v;
    const float pos = (l == 0) ? s0v : s1v;
    const float neg = (l == 0) ? s1v : s0v;

    const float n1 = (float)BB - n0;
    const float cnt_same = ((l == 0) ? n0 : n1) - 1.0f;
    const float cnt_diff = (l == 0) ? n1 : n0;

    float r_con = 0.0f;
    if (cnt_same > 0.0f && cnt_diff > 0.0f)
        r_con = logf(pos + neg + 1e-8f) - logf(pos);

    float tot = (r_center + r_margin + 0.5f * r_con) * (1.0f / (float)BB);

    #pragma unroll
    for (int m = 1; m < 64; m <<= 1) tot += __shfl_xor(tot, m);
    if (lane == 0) atomicAdd(out, tot);
}

// ---------------------------------------------------------------------------
// launch: 3 kernel nodes.
// ---------------------------------------------------------------------------
extern "C" void kernel_launch(void* const* d_in, const int* in_sizes, int n_in,
                              void* d_out, int out_size, void* d_ws, size_t ws_size,
                              hipStream_t stream) {
    const float* feat   = (const float*)d_in[0];
    const int*   labels = (const int*)d_in[1];
    const float* center = (const float*)d_in[2];
    const float* rsigma = (const float*)d_in[3];
    float* out = (float*)d_out;

    char* ws = (char*)d_ws;
    __hip_bfloat16* fnf = (__hip_bfloat16*)ws;                    // B*D bf16 = 4 MB, fragment order
    float* dist_sq = (float*)(ws + (size_t)BB * DD * 2);          // B floats
    float* S_all   = dist_sq + BB;                                // B floats (zeroed)
    float* S_1     = S_all + BB;                                  // B floats (zeroed)
    float* rowsum  = S_1 + BB;                                    // B floats
    float* rownsq  = rowsum + BB;                                 // B floats
    float* labf    = rownsq + BB;                                 // B floats

    prep_kernel<<<dim3(BB / 4), dim3(256), 0, stream>>>(feat, labels, center, fnf,
                                                        dist_sq, rowsum, rownsq, labf,
                                                        S_all, out);
    gram_kernel<<<dim3(64 * 16), dim3(256), 0, stream>>>(fnf, labf, S_all, S_1);
    finalize_kernel<<<dim3(BB / 256), dim3(256), 0, stream>>>(labels, dist_sq, S_all, S_1,
                                                              rowsum, rownsq, rsigma, out);
}